// Round 4
// baseline (200.689 us; speedup 1.0000x reference)
//
#include <hip/hip_runtime.h>
#include <math.h>

#define EMB 512
#define NH 8
#define HD 64
#define BB 2
#define SS 1024
#define ROWS (BB * SS) /* 2048 */

typedef __attribute__((ext_vector_type(8))) short bhalf8;
typedef __attribute__((ext_vector_type(4))) float f32x4;
typedef __attribute__((ext_vector_type(8))) unsigned short us8;
typedef unsigned short ushort_t;

__device__ __forceinline__ unsigned short f2bf(float x) {
  unsigned u = __float_as_uint(x);
  u = (u + 0x7FFFu + ((u >> 16) & 1u)) >> 16;
  return (unsigned short)u;
}

__device__ __forceinline__ float fast_tanh(float x) {
  x = fminf(15.f, fmaxf(-15.f, x));
  const float e = __expf(2.f * x);
  return (e - 1.f) / (e + 1.f);
}

// ============================================================
// Convert fp32 -> bf16 (8 elems/thread)
// ============================================================
__global__ __launch_bounds__(256) void convf2b_kernel(
    const float* __restrict__ src, ushort_t* __restrict__ dst, int n) {
  const int i = (blockIdx.x * 256 + threadIdx.x) * 8;
  if (i >= n) return;
  const float4 a = *(const float4*)&src[i];
  const float4 b = *(const float4*)&src[i + 4];
  us8 o;
  o[0] = f2bf(a.x); o[1] = f2bf(a.y); o[2] = f2bf(a.z); o[3] = f2bf(a.w);
  o[4] = f2bf(b.x); o[5] = f2bf(b.y); o[6] = f2bf(b.z); o[7] = f2bf(b.w);
  *(us8*)&dst[i] = o;
}

// ============================================================
// Weight transpose + convert: W[K][N] fp32 -> Wt[N][K] bf16
// ============================================================
__global__ __launch_bounds__(256) void wtrans_kernel(
    const float* __restrict__ Wu, const float* __restrict__ Wq,
    const float* __restrict__ Wkv, const float* __restrict__ Wp,
    ushort_t* __restrict__ WtAll, ushort_t* __restrict__ WpT) {
  const int z = blockIdx.z;
  const float* src;
  ushort_t* dst;
  int K, N;
  if (z == 0) { src = Wu;  dst = WtAll;              K = 512; N = 512; }
  else if (z == 1) { src = Wq;  dst = WtAll + 512 * 512;  K = 512; N = 512; }
  else if (z == 2) { src = Wkv; dst = WtAll + 1024 * 512; K = 512; N = 1024; }
  else { src = Wp;  dst = WpT;               K = 128; N = 512; }
  const int n0 = blockIdx.x * 64, k0 = blockIdx.y * 64;
  if (n0 >= N || k0 >= K) return;
  const int tid = threadIdx.x;

  __shared__ float sT[64 * 65];
#pragma unroll
  for (int i = 0; i < 4; ++i) {
    const int idx = i * 256 + tid;
    const int r = idx >> 4, c4 = (idx & 15) * 4;
    const float4 v = *(const float4*)&src[(size_t)(k0 + r) * N + n0 + c4];
    sT[(c4 + 0) * 65 + r] = v.x;
    sT[(c4 + 1) * 65 + r] = v.y;
    sT[(c4 + 2) * 65 + r] = v.z;
    sT[(c4 + 3) * 65 + r] = v.w;
  }
  __syncthreads();
#pragma unroll
  for (int i = 0; i < 2; ++i) {
    const int idx = i * 256 + tid;
    const int rr = idx >> 3, ch = (idx & 7) * 8;
    us8 o;
#pragma unroll
    for (int jj = 0; jj < 8; ++jj) o[jj] = f2bf(sT[rr * 65 + ch + jj]);
    *(us8*)&dst[(size_t)(n0 + rr) * K + k0 + ch] = o;
  }
}

// ============================================================
// proj MFMA GEMM: D[m][n] = sum_k A16[m][k] * Wt[n][k]
// M=2048, N=2048, K=512. Tile 128(M)x64(N), BK=64, grid (32,16)=512
// blocks (2/CU). 4 waves: wm=(w>>1)*64, wn=(w&1)*32 -> 64x32/wave.
// Register-prefetch double buffering. vh written TRANSPOSED (vhT).
// ============================================================
__global__ __launch_bounds__(256, 2) void proj_mfma_kernel(
    const ushort_t* __restrict__ A16, const ushort_t* __restrict__ Wt,
    const float* __restrict__ Wu_b, const float* __restrict__ Wq_b,
    const float* __restrict__ Wkv_b, const float* __restrict__ Buc,
    const float* __restrict__ Bup, const float* __restrict__ Bfc,
    const float* __restrict__ Bfp, ushort_t* __restrict__ qcU,
    ushort_t* __restrict__ qpU, ushort_t* __restrict__ qcF,
    ushort_t* __restrict__ qpF, ushort_t* __restrict__ khB,
    ushort_t* __restrict__ vhT) {
  const int nb = blockIdx.x * 64, mb = blockIdx.y * 128;
  const int tid = threadIdx.x;
  const int w = tid >> 6, lane = tid & 63;
  const int ln = lane & 15, quad = lane >> 4;
  const int wm = (w >> 1) * 64, wn = (w & 1) * 32;

  __shared__ __align__(16) ushort_t sA[128 * 72];
  __shared__ __align__(16) ushort_t sB[64 * 72];

  f32x4 acc[4][2];
#pragma unroll
  for (int rt = 0; rt < 4; ++rt)
#pragma unroll
    for (int ct = 0; ct < 2; ++ct) acc[rt][ct] = (f32x4){0.f, 0.f, 0.f, 0.f};

  uint4 pA[4], pB[2];
#pragma unroll
  for (int i = 0; i < 4; ++i) {
    const int idx = tid + i * 256;
    pA[i] = *(const uint4*)&A16[(size_t)(mb + (idx >> 3)) * 512 + (idx & 7) * 8];
  }
#pragma unroll
  for (int i = 0; i < 2; ++i) {
    const int idx = tid + i * 256;
    pB[i] = *(const uint4*)&Wt[(size_t)(nb + (idx >> 3)) * 512 + (idx & 7) * 8];
  }

  for (int k0 = 0; k0 < 512; k0 += 64) {
    __syncthreads();
#pragma unroll
    for (int i = 0; i < 4; ++i) {
      const int idx = tid + i * 256;
      *(uint4*)&sA[(idx >> 3) * 72 + (idx & 7) * 8] = pA[i];
    }
#pragma unroll
    for (int i = 0; i < 2; ++i) {
      const int idx = tid + i * 256;
      *(uint4*)&sB[(idx >> 3) * 72 + (idx & 7) * 8] = pB[i];
    }
    __syncthreads();
    if (k0 < 448) {
      const int k1 = k0 + 64;
#pragma unroll
      for (int i = 0; i < 4; ++i) {
        const int idx = tid + i * 256;
        pA[i] = *(const uint4*)&A16[(size_t)(mb + (idx >> 3)) * 512 + k1 +
                                    (idx & 7) * 8];
      }
#pragma unroll
      for (int i = 0; i < 2; ++i) {
        const int idx = tid + i * 256;
        pB[i] = *(const uint4*)&Wt[(size_t)(nb + (idx >> 3)) * 512 + k1 +
                                   (idx & 7) * 8];
      }
    }
#pragma unroll
    for (int kc = 0; kc < 2; ++kc) {
      bhalf8 af[4], bf_[2];
#pragma unroll
      for (int rt = 0; rt < 4; ++rt)
        af[rt] =
            *(const bhalf8*)&sA[(wm + rt * 16 + ln) * 72 + kc * 32 + quad * 8];
#pragma unroll
      for (int ct = 0; ct < 2; ++ct)
        bf_[ct] =
            *(const bhalf8*)&sB[(wn + ct * 16 + ln) * 72 + kc * 32 + quad * 8];
#pragma unroll
      for (int rt = 0; rt < 4; ++rt)
#pragma unroll
        for (int ct = 0; ct < 2; ++ct)
          acc[rt][ct] = __builtin_amdgcn_mfma_f32_16x16x32_bf16(
              af[rt], bf_[ct], acc[rt][ct], 0, 0, 0);
    }
  }

  if (nb < 512) {
#pragma unroll
    for (int ct = 0; ct < 2; ++ct) {
      const int n = nb + wn + ct * 16 + ln;
      const float wb = Wu_b[n], bc = Buc[n], bp = Bup[n];
#pragma unroll
      for (int rt = 0; rt < 4; ++rt)
#pragma unroll
        for (int r = 0; r < 4; ++r) {
          const int m = mb + wm + rt * 16 + quad * 4 + r;
          const float v = acc[rt][ct][r] + wb;
          qcU[(size_t)m * 512 + n] = f2bf(fast_tanh(v + bc));
          qpU[(size_t)m * 512 + n] = f2bf(fast_tanh(v + bp));
        }
    }
  } else if (nb < 1024) {
#pragma unroll
    for (int ct = 0; ct < 2; ++ct) {
      const int n = nb + wn + ct * 16 + ln;
      const int nn = n - 512;
      const float wb = Wq_b[nn], bc = Bfc[nn], bp = Bfp[nn];
#pragma unroll
      for (int rt = 0; rt < 4; ++rt)
#pragma unroll
        for (int r = 0; r < 4; ++r) {
          const int m = mb + wm + rt * 16 + quad * 4 + r;
          const float v = acc[rt][ct][r] + wb;
          qcF[(size_t)m * 512 + nn] = f2bf(fast_tanh(v + bc));
          qpF[(size_t)m * 512 + nn] = f2bf(fast_tanh(v + bp));
        }
    }
  } else if (nb < 1536) {
#pragma unroll
    for (int ct = 0; ct < 2; ++ct) {
      const int n = nb + wn + ct * 16 + ln;
      const int nn = n - 1024;
      const float wb = Wkv_b[nn];
#pragma unroll
      for (int rt = 0; rt < 4; ++rt)
#pragma unroll
        for (int r = 0; r < 4; ++r) {
          const int m = mb + wm + rt * 16 + quad * 4 + r;
          khB[(size_t)m * 512 + nn] = f2bf(fast_tanh(acc[rt][ct][r] + wb));
        }
    }
  } else {
    // vh -> transposed vhT[(b*512 + nn)*1024 + k], vectorized along k
#pragma unroll
    for (int ct = 0; ct < 2; ++ct) {
      const int n = nb + wn + ct * 16 + ln;
      const float wb = Wkv_b[n - 1024];
      const int nn = n - 1536;
#pragma unroll
      for (int rt = 0; rt < 4; ++rt) {
        const int m0 = mb + wm + rt * 16 + quad * 4;
        ushort4 o;
        o.x = f2bf(fast_tanh(acc[rt][ct][0] + wb));
        o.y = f2bf(fast_tanh(acc[rt][ct][1] + wb));
        o.z = f2bf(fast_tanh(acc[rt][ct][2] + wb));
        o.w = f2bf(fast_tanh(acc[rt][ct][3] + wb));
        *(ushort4*)&vhT[((size_t)(m0 >> 10) * 512 + nn) * 1024 + (m0 & 1023)] =
            o;
      }
    }
  }
}

// ============================================================
// pe MFMA GEMM: kp[m][n] = tanh(sum_k gpe16[m][k]*WpT[n][k] + Wp_b[n])
// ============================================================
__global__ __launch_bounds__(256) void pe_mfma_kernel(
    const ushort_t* __restrict__ A16, const ushort_t* __restrict__ WpT,
    const float* __restrict__ Wp_b, ushort_t* __restrict__ kpB) {
  const int nb = blockIdx.x * 128, mb = blockIdx.y * 128;
  const int tid = threadIdx.x;
  const int w = tid >> 6, lane = tid & 63;
  const int ln = lane & 15, quad = lane >> 4;
  const int wm = (w >> 1) * 64, wn = (w & 1) * 64;

  __shared__ __align__(16) ushort_t sA[128 * 72];
  __shared__ __align__(16) ushort_t sB[128 * 72];

  f32x4 acc[4][4];
#pragma unroll
  for (int rt = 0; rt < 4; ++rt)
#pragma unroll
    for (int ct = 0; ct < 4; ++ct) acc[rt][ct] = (f32x4){0.f, 0.f, 0.f, 0.f};

#pragma unroll
  for (int k0 = 0; k0 < 128; k0 += 64) {
    __syncthreads();
#pragma unroll
    for (int i = 0; i < 4; ++i) {
      const int idx = i * 256 + tid;
      const int r = idx >> 3, ch = (idx & 7) * 8;
      *(uint4*)&sA[r * 72 + ch] =
          *(const uint4*)&A16[(size_t)(mb + r) * 128 + k0 + ch];
      *(uint4*)&sB[r * 72 + ch] =
          *(const uint4*)&WpT[(size_t)(nb + r) * 128 + k0 + ch];
    }
    __syncthreads();
#pragma unroll
    for (int kc = 0; kc < 2; ++kc) {
      bhalf8 af[4], bf_[4];
#pragma unroll
      for (int rt = 0; rt < 4; ++rt)
        af[rt] =
            *(const bhalf8*)&sA[(wm + rt * 16 + ln) * 72 + kc * 32 + quad * 8];
#pragma unroll
      for (int ct = 0; ct < 4; ++ct)
        bf_[ct] =
            *(const bhalf8*)&sB[(wn + ct * 16 + ln) * 72 + kc * 32 + quad * 8];
#pragma unroll
      for (int rt = 0; rt < 4; ++rt)
#pragma unroll
        for (int ct = 0; ct < 4; ++ct)
          acc[rt][ct] = __builtin_amdgcn_mfma_f32_16x16x32_bf16(
              af[rt], bf_[ct], acc[rt][ct], 0, 0, 0);
    }
  }

#pragma unroll
  for (int ct = 0; ct < 4; ++ct) {
    const int n = nb + wn + ct * 16 + ln;
    const float wb = Wp_b[n];
#pragma unroll
    for (int rt = 0; rt < 4; ++rt)
#pragma unroll
      for (int r = 0; r < 4; ++r) {
        const int m = mb + wm + rt * 16 + quad * 4 + r;
        kpB[(size_t)m * 512 + n] = f2bf(fast_tanh(acc[rt][ct][r] + wb));
      }
  }
}

// ============================================================
// Kernel 2: flash MFMA attention, static-max softmax.
// Scores bounded: all operands are tanh outputs -> |S| <= 128/8 = 16.
// p = exp(s-16); no running max, no rescale; lsum reduced once at end.
// jt reversed on t so co-resident block pairs (i, i+256) sum to 17 iters.
// ============================================================
__global__ __launch_bounds__(256, 2) void attn_mfma_kernel(
    const ushort_t* __restrict__ qcU, const ushort_t* __restrict__ qpU,
    const ushort_t* __restrict__ qcF, const ushort_t* __restrict__ qpF,
    const ushort_t* __restrict__ khB, const ushort_t* __restrict__ kpB,
    const ushort_t* __restrict__ vhT, float* __restrict__ attO) {
  const int t = blockIdx.z;
  const int jt = t ? (int)blockIdx.x : 15 - (int)blockIdx.x;  // balance
  const int h = blockIdx.y & 7, b = blockIdx.y >> 3;
  const int tid = threadIdx.x;
  const int w = tid >> 6;
  const int lane = tid & 63;
  const int ln = lane & 15, quad = lane >> 4;

  __shared__ __align__(16) ushort_t sKQ[64 * 136];  // Q2 then K2 (union)
  __shared__ __align__(16) ushort_t sVt[64 * 72];
  __shared__ __align__(16) ushort_t sP[64 * 72];

  const ushort_t* qcS = t ? qcF : qcU;
  const ushort_t* qpS = t ? qpF : qpU;

  // ---- stage Q2 [64][128] into sKQ ----
  uint4 qr[4];
#pragma unroll
  for (int i = 0; i < 2; ++i) {
    const int idx = tid + i * 256;
    const int r = idx >> 3, c = (idx & 7) * 8;
    const int j = jt * 64 + r;
    const size_t qrow = (size_t)(b * SS + j);
    qr[i] = *(const uint4*)&qcS[qrow * 512 + h * 64 + c];
    if (b == 0) {
      qr[2 + i] = (j == SS - 1)
                      ? make_uint4(0u, 0u, 0u, 0u)
                      : *(const uint4*)&qpS[(qrow + 1) * 512 + h * 64 + c];
    } else {
      qr[2 + i] = *(const uint4*)&qpS[qrow * 512 + h * 64 + c];
    }
  }
  // prefetch kt=0
  uint4 pk[4], pv[2];
  {
#pragma unroll
    for (int i = 0; i < 2; ++i) {
      const int idx = tid + i * 256;
      const int r = idx >> 3, c = (idx & 7) * 8;
      const size_t krow = (size_t)(b * SS + r);
      pk[i] = *(const uint4*)&khB[krow * 512 + h * 64 + c];
      pk[2 + i] = *(const uint4*)&kpB[krow * 512 + h * 64 + c];
      pv[i] = *(const uint4*)&vhT[((size_t)(b * 512) + h * 64 + r) * 1024 + c];
    }
  }
#pragma unroll
  for (int i = 0; i < 2; ++i) {
    const int idx = tid + i * 256;
    const int r = idx >> 3, c = (idx & 7) * 8;
    *(uint4*)&sKQ[r * 136 + c] = qr[i];
    *(uint4*)&sKQ[r * 136 + 64 + c] = qr[2 + i];
  }
  __syncthreads();

  bhalf8 aq[4];
#pragma unroll
  for (int kc = 0; kc < 4; ++kc)
    aq[kc] = *(const bhalf8*)&sKQ[(w * 16 + ln) * 136 + kc * 32 + quad * 8];

  f32x4 oacc[4];
#pragma unroll
  for (int ct = 0; ct < 4; ++ct) oacc[ct] = (f32x4){0.f, 0.f, 0.f, 0.f};
  float lsum[4] = {0.f, 0.f, 0.f, 0.f};

  for (int kt = 0; kt <= jt; ++kt) {
    __syncthreads();  // prev-iter reads (and aq reads on iter 0) done
#pragma unroll
    for (int i = 0; i < 2; ++i) {
      const int idx = tid + i * 256;
      const int r = idx >> 3, c = (idx & 7) * 8;
      *(uint4*)&sKQ[r * 136 + c] = pk[i];
      *(uint4*)&sKQ[r * 136 + 64 + c] = pk[2 + i];
      *(uint4*)&sVt[r * 72 + c] = pv[i];
    }
    __syncthreads();
    if (kt < jt) {
      const int k1 = (kt + 1) * 64;
#pragma unroll
      for (int i = 0; i < 2; ++i) {
        const int idx = tid + i * 256;
        const int r = idx >> 3, c = (idx & 7) * 8;
        const size_t krow = (size_t)(b * SS + k1 + r);
        pk[i] = *(const uint4*)&khB[krow * 512 + h * 64 + c];
        pk[2 + i] = *(const uint4*)&kpB[krow * 512 + h * 64 + c];
        pv[i] = *(const uint4*)&vhT[((size_t)(b * 512) + h * 64 + r) * 1024 +
                                    k1 + c];
      }
    }

    // S = Q2 @ K2^T
    f32x4 sacc[4];
#pragma unroll
    for (int ct = 0; ct < 4; ++ct) {
      sacc[ct] = (f32x4){0.f, 0.f, 0.f, 0.f};
#pragma unroll
      for (int kc = 0; kc < 4; ++kc) {
        const bhalf8 bk =
            *(const bhalf8*)&sKQ[(ct * 16 + ln) * 136 + kc * 32 + quad * 8];
        sacc[ct] = __builtin_amdgcn_mfma_f32_16x16x32_bf16(aq[kc], bk,
                                                           sacc[ct], 0, 0, 0);
      }
    }

    // p = exp(s/8 - 16), causal mask on diagonal supertile
    const bool diag = (kt == jt);
#pragma unroll
    for (int ct = 0; ct < 4; ++ct)
#pragma unroll
      for (int r = 0; r < 4; ++r) {
        float p;
        if (diag && (ct * 16 + ln > w * 16 + quad * 4 + r))
          p = 0.f;
        else
          p = __expf(sacc[ct][r] * 0.125f - 16.f);
        sacc[ct][r] = p;
        lsum[r] += p;
      }

    // P -> LDS (wave-private rows; no barrier needed)
#pragma unroll
    for (int ct = 0; ct < 4; ++ct)
#pragma unroll
      for (int r = 0; r < 4; ++r)
        sP[(w * 16 + quad * 4 + r) * 72 + ct * 16 + ln] = f2bf(sacc[ct][r]);

    // O += P @ V
#pragma unroll
    for (int kc = 0; kc < 2; ++kc) {
      const bhalf8 ap =
          *(const bhalf8*)&sP[(w * 16 + ln) * 72 + kc * 32 + quad * 8];
#pragma unroll
      for (int ct = 0; ct < 4; ++ct) {
        const bhalf8 bv =
            *(const bhalf8*)&sVt[(ct * 16 + ln) * 72 + kc * 32 + quad * 8];
        oacc[ct] =
            __builtin_amdgcn_mfma_f32_16x16x32_bf16(ap, bv, oacc[ct], 0, 0, 0);
      }
    }
  }

  // reduce lsum across the 16 ln-lanes of each quad; write O/l
#pragma unroll
  for (int r = 0; r < 4; ++r) {
    float s = lsum[r];
    s += __shfl_xor(s, 1);
    s += __shfl_xor(s, 2);
    s += __shfl_xor(s, 4);
    s += __shfl_xor(s, 8);
    const float inv = 1.f / s;
    const int j = jt * 64 + w * 16 + quad * 4 + r;
    const size_t orow = ((size_t)t * ROWS + b * SS + j) * 512 + h * 64;
#pragma unroll
    for (int ct = 0; ct < 4; ++ct)
      attO[orow + ct * 16 + ln] = oacc[ct][r] * inv;
  }
}

// ============================================================
// Kernel 3: residual + layernorm
// ============================================================
__global__ __launch_bounds__(64) void ln_kernel(
    const float* __restrict__ u_emb, const float* __restrict__ f_emb,
    const float* __restrict__ attO, float* __restrict__ out) {
  const int rid = blockIdx.x;
  const int t = rid >> 11, row = rid & 2047;
  const float* resid = t ? f_emb : u_emb;
  const int tid = threadIdx.x;
  const size_t base = (size_t)row * 512;
  const size_t abase = ((size_t)t * ROWS + row) * 512;

  const float4 r0 = ((const float4*)&resid[base])[tid];
  const float4 r1 = ((const float4*)&resid[base])[tid + 64];
  const float4 a0 = ((const float4*)&attO[abase])[tid];
  const float4 a1 = ((const float4*)&attO[abase])[tid + 64];
  float4 y0, y1;
  y0.x = r0.x + a0.x; y0.y = r0.y + a0.y; y0.z = r0.z + a0.z; y0.w = r0.w + a0.w;
  y1.x = r1.x + a1.x; y1.y = r1.y + a1.y; y1.z = r1.z + a1.z; y1.w = r1.w + a1.w;

  float s = y0.x + y0.y + y0.z + y0.w + y1.x + y1.y + y1.z + y1.w;
  float q = y0.x * y0.x + y0.y * y0.y + y0.z * y0.z + y0.w * y0.w +
            y1.x * y1.x + y1.y * y1.y + y1.z * y1.z + y1.w * y1.w;
#pragma unroll
  for (int off = 1; off < 64; off <<= 1) {
    s += __shfl_xor(s, off);
    q += __shfl_xor(q, off);
  }
  const float mean = s * (1.f / 512.f);
  const float var = q * (1.f / 512.f) - mean * mean;
  const float rstd = rsqrtf(var + 1e-5f);

  float4 o0, o1;
  o0.x = (y0.x - mean) * rstd; o0.y = (y0.y - mean) * rstd;
  o0.z = (y0.z - mean) * rstd; o0.w = (y0.w - mean) * rstd;
  o1.x = (y1.x - mean) * rstd; o1.y = (y1.y - mean) * rstd;
  o1.z = (y1.z - mean) * rstd; o1.w = (y1.w - mean) * rstd;
  ((float4*)&out[abase])[tid] = o0;
  ((float4*)&out[abase])[tid + 64] = o1;
}

// ============================================================
extern "C" void kernel_launch(void* const* d_in, const int* in_sizes, int n_in,
                              void* d_out, int out_size, void* d_ws,
                              size_t ws_size, hipStream_t stream) {
  (void)in_sizes; (void)n_in; (void)out_size; (void)ws_size;
  const float* u_emb = (const float*)d_in[0];
  const float* f_emb = (const float*)d_in[1];
  const float* gpe = (const float*)d_in[2];
  const float* Wq_w = (const float*)d_in[5];
  const float* Wq_b = (const float*)d_in[6];
  const float* Wkv_w = (const float*)d_in[7];
  const float* Wkv_b = (const float*)d_in[8];
  const float* Wp_w = (const float*)d_in[9];
  const float* Wp_b = (const float*)d_in[10];
  const float* Wu_w = (const float*)d_in[11];
  const float* Wu_b = (const float*)d_in[12];
  const float* Bfc = (const float*)d_in[13];
  const float* Bfp = (const float*)d_in[14];
  const float* Buc = (const float*)d_in[15];
  const float* Bup = (const float*)d_in[16];
  float* out = (float*)d_out;

  ushort_t* ws = (ushort_t*)d_ws;
  const size_t SZ = (size_t)ROWS * EMB;  // 1048576 elems
  ushort_t* qcU = ws + 0 * SZ;
  ushort_t* qpU = ws + 1 * SZ;
  ushort_t* qcF = ws + 2 * SZ;
  ushort_t* qpF = ws + 3 * SZ;
  ushort_t* khB = ws + 4 * SZ;
  ushort_t* vhT = ws + 5 * SZ;  // [b][h*64+d][k] transposed
  ushort_t* kpB = ws + 6 * SZ;
  float* attO = (float*)(ws + 7 * SZ);
  // overlay (consumed before attn writes attO):
  ushort_t* ov = ws + 7 * SZ;
  ushort_t* f16emb = ov;
  ushort_t* gpe16 = ov + SZ;
  ushort_t* WtAll = ov + SZ + 262144;
  ushort_t* WpT = ov + 2 * SZ + 262144;

  dim3 blk(256);
  hipLaunchKernelGGL(convf2b_kernel, dim3(512), blk, 0, stream, f_emb, f16emb,
                     (int)SZ);
  hipLaunchKernelGGL(convf2b_kernel, dim3(128), blk, 0, stream, gpe, gpe16,
                     ROWS * 128);
  hipLaunchKernelGGL(wtrans_kernel, dim3(16, 8, 4), blk, 0, stream, Wu_w, Wq_w,
                     Wkv_w, Wp_w, WtAll, WpT);
  hipLaunchKernelGGL(proj_mfma_kernel, dim3(32, 16), blk, 0, stream, f16emb,
                     WtAll, Wu_b, Wq_b, Wkv_b, Buc, Bup, Bfc, Bfp, qcU, qpU,
                     qcF, qpF, khB, vhT);
  hipLaunchKernelGGL(pe_mfma_kernel, dim3(4, 16), blk, 0, stream, gpe16, WpT,
                     Wp_b, kpB);
  dim3 g3(16, 16, 2);
  hipLaunchKernelGGL(attn_mfma_kernel, g3, blk, 0, stream, qcU, qpU, qcF, qpF,
                     khB, kpB, vhT, attO);
  dim3 g4(4096);
  hipLaunchKernelGGL(ln_kernel, g4, dim3(64), 0, stream, u_emb, f_emb, attO,
                     out);
}